// Round 1
// baseline (445.889 us; speedup 1.0000x reference)
//
#include <hip/hip_runtime.h>
#include <hip/hip_bf16.h>
#include <stdint.h>

#define N_NODES 20000
#define N_EDGES 160000
#define DIN 512
#define DOUT 512
#define NBUCKET 11
#define KDIM 1024   // [h | feats]

typedef float f32x4 __attribute__((ext_vector_type(4)));
typedef __attribute__((ext_vector_type(8))) __bf16 bf16x8;

static __device__ __forceinline__ unsigned short f2bf(float f) {
    union { float f; unsigned u; } v; v.f = f;
    unsigned r = v.u + 0x7FFFu + ((v.u >> 16) & 1u);
    return (unsigned short)(r >> 16);
}

// ---------- CSR build ----------
__global__ void k_deg(const int* __restrict__ dst, int* __restrict__ deg) {
    int e = blockIdx.x * 256 + threadIdx.x;
    if (e < N_EDGES) atomicAdd(&deg[dst[e]], 1);
}

__global__ void k_scan(const int* __restrict__ deg, int* __restrict__ offsets) {
    __shared__ int part[1024];
    int t = threadIdx.x;
    const int CH = 20;   // 1024*20 >= 20000
    int s0 = t * CH, s1 = min(s0 + CH, N_NODES);
    int s = 0;
    for (int i = s0; i < s1; ++i) s += deg[i];
    part[t] = s; __syncthreads();
    for (int off = 1; off < 1024; off <<= 1) {
        int v = part[t];
        int a = (t >= off) ? part[t - off] : 0;
        __syncthreads();
        part[t] = v + a;
        __syncthreads();
    }
    int base = (t == 0) ? 0 : part[t - 1];
    for (int i = s0; i < s1; ++i) { offsets[i] = base; base += deg[i]; }
    if (t == 1023) offsets[N_NODES] = part[1023];
}

__global__ void k_bucket(const int* __restrict__ deg, int* __restrict__ bucket_cnt,
                         int* __restrict__ bucket_nodes) {
    int v = blockIdx.x * 256 + threadIdx.x;
    if (v >= N_NODES) return;
    int d = min(deg[v], NBUCKET - 1);
    int slot = atomicAdd(&bucket_cnt[d], 1);
    bucket_nodes[d * N_NODES + slot] = v;
}

__global__ void k_scatter(const int* __restrict__ src, const int* __restrict__ dst,
                          const int* __restrict__ offsets, int* __restrict__ cursor,
                          int* __restrict__ eidx) {
    int e = blockIdx.x * 256 + threadIdx.x;
    if (e >= N_EDGES) return;
    int v = dst[e];
    int slot = atomicAdd(&cursor[v], 1);
    eidx[offsets[v] + slot] = src[e];
}

// ---------- X = [h | feats] in bf16 ----------
__global__ __launch_bounds__(128)
void k_build_x(const float* __restrict__ feats, const int* __restrict__ eidx,
               const int* __restrict__ offsets, unsigned short* __restrict__ X) {
    int n = blockIdx.x;
    int col = threadIdx.x * 4;
    int s = offsets[n], e = offsets[n + 1];
    f32x4 acc = {0.f, 0.f, 0.f, 0.f};
    for (int i = s; i < e; ++i) {
        int u = eidx[i];
        f32x4 f = *(const f32x4*)(feats + (size_t)u * DIN + col);
        acc += f;
    }
    unsigned short* xr = X + (size_t)n * KDIM;
    ushort4 hv;
    hv.x = f2bf(acc[0]); hv.y = f2bf(acc[1]); hv.z = f2bf(acc[2]); hv.w = f2bf(acc[3]);
    *(ushort4*)(xr + col) = hv;
    f32x4 sf = *(const f32x4*)(feats + (size_t)n * DIN + col);
    ushort4 sv;
    sv.x = f2bf(sf[0]); sv.y = f2bf(sf[1]); sv.z = f2bf(sf[2]); sv.w = f2bf(sf[3]);
    *(ushort4*)(xr + DIN + col) = sv;
}

// ---------- weights -> Wt[d][n][k] bf16 (transposed, K contiguous) ----------
__global__ __launch_bounds__(256)
void k_wt(const float* __restrict__ Wl, const float* __restrict__ Wr,
          unsigned short* __restrict__ Wt) {
    __shared__ float tile[32][33];
    int d = blockIdx.z, n0 = blockIdx.y * 32, k0 = blockIdx.x * 32;
    int t = threadIdx.x;
    int c = t & 31, r0 = t >> 5;   // r0 in 0..7
    const float* srcp = (k0 < DIN) ? (Wl + (size_t)d * DIN * DOUT)
                                   : (Wr + (size_t)d * DIN * DOUT - (size_t)DIN * DOUT);
    for (int rr = 0; rr < 4; ++rr) {
        int r = r0 + rr * 8;
        tile[r][c] = srcp[(size_t)(k0 + r) * DOUT + n0 + c];
    }
    __syncthreads();
    for (int rr = 0; rr < 4; ++rr) {
        int r = r0 + rr * 8;   // row in n
        Wt[((size_t)d * DOUT + n0 + r) * KDIM + k0 + c] = f2bf(tile[c][r]);
    }
}

// ---------- bucketed MFMA GEMM: out_pre[rid] = X[rid] @ Wt[d]^T + bl[d] ----------
__global__ __launch_bounds__(256)
void k_gemm(const unsigned short* __restrict__ X, const unsigned short* __restrict__ Wt,
            const int* __restrict__ bucket_nodes, const int* __restrict__ bucket_cnt,
            const float* __restrict__ bl, float* __restrict__ out_pre) {
    int d = blockIdx.z;
    int cnt = bucket_cnt[d];
    int m0 = blockIdx.x * 64;
    if (m0 >= cnt) return;
    int n0 = blockIdx.y * 64;

    __shared__ int ridS[64];
    __shared__ unsigned short As[64 * 40];   // row stride 40 (+8 pad)
    __shared__ unsigned short Bs[64 * 40];

    int t = threadIdx.x;
    if (t < 64) {
        int gm = m0 + t;
        ridS[t] = (gm < cnt) ? bucket_nodes[d * N_NODES + gm] : -1;
    }
    __syncthreads();

    int m = t >> 2, seg = t & 3;             // staging: 64 rows x 4 segs of 16B
    int rid = ridS[m];
    const size_t arow = (rid >= 0) ? ((size_t)rid * KDIM + seg * 8) : 0;
    const size_t brow = ((size_t)d * DOUT + n0 + m) * KDIM + seg * 8;

    int w = t >> 6, lane = t & 63;
    int wm = (w & 1) * 32, wn = (w >> 1) * 32;
    int lm = lane & 15, q = lane >> 4;

    f32x4 acc00 = {0,0,0,0}, acc01 = {0,0,0,0}, acc10 = {0,0,0,0}, acc11 = {0,0,0,0};

    for (int kt = 0; kt < KDIM / 32; ++kt) {
        uint4 av = make_uint4(0, 0, 0, 0);
        if (rid >= 0) av = *(const uint4*)(X + arow + kt * 32);
        uint4 bv = *(const uint4*)(Wt + brow + kt * 32);
        *(uint4*)&As[m * 40 + seg * 8] = av;
        *(uint4*)&Bs[m * 40 + seg * 8] = bv;
        __syncthreads();

        bf16x8 a0 = *(bf16x8*)&As[(wm + lm) * 40 + q * 8];
        bf16x8 a1 = *(bf16x8*)&As[(wm + 16 + lm) * 40 + q * 8];
        bf16x8 b0 = *(bf16x8*)&Bs[(wn + lm) * 40 + q * 8];
        bf16x8 b1 = *(bf16x8*)&Bs[(wn + 16 + lm) * 40 + q * 8];
        acc00 = __builtin_amdgcn_mfma_f32_16x16x32_bf16(a0, b0, acc00, 0, 0, 0);
        acc01 = __builtin_amdgcn_mfma_f32_16x16x32_bf16(a0, b1, acc01, 0, 0, 0);
        acc10 = __builtin_amdgcn_mfma_f32_16x16x32_bf16(a1, b0, acc10, 0, 0, 0);
        acc11 = __builtin_amdgcn_mfma_f32_16x16x32_bf16(a1, b1, acc11, 0, 0, 0);
        __syncthreads();
    }

    const float* blr = bl + d * DOUT + n0;
    f32x4 accs[2][2] = {{acc00, acc01}, {acc10, acc11}};
    for (int mt = 0; mt < 2; ++mt)
        for (int r = 0; r < 4; ++r) {
            int row = wm + mt * 16 + q * 4 + r;
            int grow = ridS[row];
            if (grow < 0) continue;
            float* orow = out_pre + (size_t)grow * DOUT + n0;
            for (int nt = 0; nt < 2; ++nt) {
                int col = wn + nt * 16 + lm;
                orow[col] = accs[mt][nt][r] + blr[col];
            }
        }
}

// ---------- batchnorm stats ----------
__global__ __launch_bounds__(256)
void k_bnstats(const float* __restrict__ out_pre, float* __restrict__ bn_sum,
               float* __restrict__ bn_sumsq) {
    int t = threadIdx.x;
    int r0 = blockIdx.x * 100;
    float s0 = 0, s1 = 0, q0 = 0, q1 = 0;
    for (int r = r0; r < r0 + 100; ++r) {
        float v0 = out_pre[(size_t)r * DOUT + t];
        float v1 = out_pre[(size_t)r * DOUT + t + 256];
        s0 += v0; q0 += v0 * v0;
        s1 += v1; q1 += v1 * v1;
    }
    atomicAdd(&bn_sum[t], s0);
    atomicAdd(&bn_sum[t + 256], s1);
    atomicAdd(&bn_sumsq[t], q0);
    atomicAdd(&bn_sumsq[t + 256], q1);
}

__global__ void k_bnfinal(const float* __restrict__ bn_sum, const float* __restrict__ bn_sumsq,
                          const float* __restrict__ gamma, const float* __restrict__ beta,
                          float* __restrict__ scale, float* __restrict__ shift) {
    int c = blockIdx.x * 256 + threadIdx.x;
    if (c >= DOUT) return;
    float mean = bn_sum[c] / (float)N_NODES;
    float var = bn_sumsq[c] / (float)N_NODES - mean * mean;
    float rs = rsqrtf(var + 1e-5f);
    float sc = gamma[c] * rs;
    scale[c] = sc;
    shift[c] = beta[c] - mean * sc;
}

// ---------- fused BN-apply + segment_max over in-neighbors + self ----------
__global__ __launch_bounds__(128)
void k_max(const float* __restrict__ out_pre, const int* __restrict__ eidx,
           const int* __restrict__ offsets, const float* __restrict__ scale,
           const float* __restrict__ shift, float* __restrict__ out) {
    int n = blockIdx.x;
    int col = threadIdx.x * 4;
    f32x4 sc = *(const f32x4*)(scale + col);
    f32x4 sh = *(const f32x4*)(shift + col);
    f32x4 v = *(const f32x4*)(out_pre + (size_t)n * DOUT + col);
    f32x4 mx = v * sc + sh;
    int s = offsets[n], e = offsets[n + 1];
    for (int i = s; i < e; ++i) {
        int u = eidx[i];
        f32x4 wv = *(const f32x4*)(out_pre + (size_t)u * DOUT + col);
        f32x4 b = wv * sc + sh;
        mx[0] = fmaxf(mx[0], b[0]);
        mx[1] = fmaxf(mx[1], b[1]);
        mx[2] = fmaxf(mx[2], b[2]);
        mx[3] = fmaxf(mx[3], b[3]);
    }
    *(f32x4*)(out + (size_t)n * DOUT + col) = mx;
}

extern "C" void kernel_launch(void* const* d_in, const int* in_sizes, int n_in,
                              void* d_out, int out_size, void* d_ws, size_t ws_size,
                              hipStream_t stream) {
    const float* feats = (const float*)d_in[0];
    const int*   src   = (const int*)d_in[1];
    const int*   dst   = (const int*)d_in[2];
    const float* Wl    = (const float*)d_in[3];
    const float* Wr    = (const float*)d_in[4];
    const float* bl    = (const float*)d_in[5];
    const float* gamma = (const float*)d_in[6];
    const float* beta  = (const float*)d_in[7];
    float* out = (float*)d_out;

    char* ws = (char*)d_ws;
    size_t off = 0;
    auto alloc = [&](size_t bytes) -> void* {
        off = (off + 255) & ~(size_t)255;
        void* p = ws + off;
        off += bytes;
        return p;
    };

    // zero-initialized region (must be contiguous & first)
    int*   deg        = (int*)alloc(N_NODES * 4);
    int*   cursor     = (int*)alloc(N_NODES * 4);
    int*   bucket_cnt = (int*)alloc(16 * 4);
    float* bn_sum     = (float*)alloc(DOUT * 4);
    float* bn_sumsq   = (float*)alloc(DOUT * 4);
    size_t zbytes = off;

    int* offsets      = (int*)alloc((N_NODES + 1) * 4);
    int* bucket_nodes = (int*)alloc((size_t)NBUCKET * N_NODES * 4);
    int* eidx         = (int*)alloc(N_EDGES * 4);
    float* scale      = (float*)alloc(DOUT * 4);
    float* shift      = (float*)alloc(DOUT * 4);
    unsigned short* X  = (unsigned short*)alloc((size_t)N_NODES * KDIM * 2);
    unsigned short* Wt = (unsigned short*)alloc((size_t)NBUCKET * DOUT * KDIM * 2);
    float* out_pre     = (float*)alloc((size_t)N_NODES * DOUT * 4);

    hipMemsetAsync(d_ws, 0, zbytes, stream);

    k_deg<<<(N_EDGES + 255) / 256, 256, 0, stream>>>(dst, deg);
    k_scan<<<1, 1024, 0, stream>>>(deg, offsets);
    k_bucket<<<(N_NODES + 255) / 256, 256, 0, stream>>>(deg, bucket_cnt, bucket_nodes);
    k_scatter<<<(N_EDGES + 255) / 256, 256, 0, stream>>>(src, dst, offsets, cursor, eidx);
    k_build_x<<<N_NODES, 128, 0, stream>>>(feats, eidx, offsets, X);
    k_wt<<<dim3(KDIM / 32, DOUT / 32, NBUCKET), 256, 0, stream>>>(Wl, Wr, Wt);
    k_gemm<<<dim3((N_NODES + 63) / 64, DOUT / 64, NBUCKET), 256, 0, stream>>>(
        X, Wt, bucket_nodes, bucket_cnt, bl, out_pre);
    k_bnstats<<<N_NODES / 100, 256, 0, stream>>>(out_pre, bn_sum, bn_sumsq);
    k_bnfinal<<<2, 256, 0, stream>>>(bn_sum, bn_sumsq, gamma, beta, scale, shift);
    k_max<<<N_NODES, 128, 0, stream>>>(out_pre, eidx, offsets, scale, shift, out);
}

// Round 2
// 396.006 us; speedup vs baseline: 1.1260x; 1.1260x over previous
//
#include <hip/hip_runtime.h>
#include <hip/hip_bf16.h>
#include <stdint.h>

#define N_NODES 20000
#define N_EDGES 160000
#define DIN 512
#define DOUT 512
#define NBUCKET 11
#define KDIM 1024   // [h | feats]
#define MAXTILES 168  // sum_d ceil(cnt_d/128) <= floor(20000/128)+11 = 167

typedef float f32x4 __attribute__((ext_vector_type(4)));
typedef __attribute__((ext_vector_type(8))) __bf16 bf16x8;

static __device__ __forceinline__ unsigned short f2bf(float f) {
    union { float f; unsigned u; } v; v.f = f;
    unsigned r = v.u + 0x7FFFu + ((v.u >> 16) & 1u);
    return (unsigned short)(r >> 16);
}

static __device__ __forceinline__ void gload_lds16(const unsigned short* g, unsigned short* l) {
    __builtin_amdgcn_global_load_lds(
        (const __attribute__((address_space(1))) unsigned int*)g,
        (__attribute__((address_space(3))) unsigned int*)l, 16, 0, 0);
}

// ---------- CSR build ----------
__global__ void k_deg(const int* __restrict__ dst, int* __restrict__ deg) {
    int e = blockIdx.x * 256 + threadIdx.x;
    if (e < N_EDGES) atomicAdd(&deg[dst[e]], 1);
}

__global__ void k_scan(const int* __restrict__ deg, int* __restrict__ offsets) {
    __shared__ int part[1024];
    int t = threadIdx.x;
    const int CH = 20;   // 1024*20 >= 20000
    int s0 = t * CH, s1 = min(s0 + CH, N_NODES);
    int s = 0;
    for (int i = s0; i < s1; ++i) s += deg[i];
    part[t] = s; __syncthreads();
    for (int off = 1; off < 1024; off <<= 1) {
        int v = part[t];
        int a = (t >= off) ? part[t - off] : 0;
        __syncthreads();
        part[t] = v + a;
        __syncthreads();
    }
    int base = (t == 0) ? 0 : part[t - 1];
    for (int i = s0; i < s1; ++i) { offsets[i] = base; base += deg[i]; }
    if (t == 1023) offsets[N_NODES] = part[1023];
}

__global__ void k_bucket(const int* __restrict__ deg, int* __restrict__ bucket_cnt,
                         int* __restrict__ bucket_nodes) {
    int v = blockIdx.x * 256 + threadIdx.x;
    if (v >= N_NODES) return;
    int d = min(deg[v], NBUCKET - 1);
    int slot = atomicAdd(&bucket_cnt[d], 1);
    bucket_nodes[d * N_NODES + slot] = v;
}

__global__ void k_tiles(const int* __restrict__ bucket_cnt, int2* __restrict__ tiles,
                        int* __restrict__ tile_cnt) {
    if (threadIdx.x != 0 || blockIdx.x != 0) return;
    int tc = 0;
    for (int d = 0; d < NBUCKET; ++d) {
        int c = bucket_cnt[d];
        for (int m0 = 0; m0 < c; m0 += 128) tiles[tc++] = make_int2(d, m0);
    }
    *tile_cnt = tc;
}

__global__ void k_scatter(const int* __restrict__ src, const int* __restrict__ dst,
                          const int* __restrict__ offsets, int* __restrict__ cursor,
                          int* __restrict__ eidx) {
    int e = blockIdx.x * 256 + threadIdx.x;
    if (e >= N_EDGES) return;
    int v = dst[e];
    int slot = atomicAdd(&cursor[v], 1);
    eidx[offsets[v] + slot] = src[e];
}

// ---------- X = [h | feats] in bf16 ----------
__global__ __launch_bounds__(128)
void k_build_x(const float* __restrict__ feats, const int* __restrict__ eidx,
               const int* __restrict__ offsets, unsigned short* __restrict__ X) {
    int n = blockIdx.x;
    int col = threadIdx.x * 4;
    int s = offsets[n], e = offsets[n + 1];
    f32x4 acc0 = {0.f, 0.f, 0.f, 0.f};
    f32x4 acc1 = {0.f, 0.f, 0.f, 0.f};
    int i = s;
    for (; i + 1 < e; i += 2) {
        int u0 = eidx[i], u1 = eidx[i + 1];
        f32x4 f0 = *(const f32x4*)(feats + (size_t)u0 * DIN + col);
        f32x4 f1 = *(const f32x4*)(feats + (size_t)u1 * DIN + col);
        acc0 += f0; acc1 += f1;
    }
    if (i < e) {
        int u = eidx[i];
        acc0 += *(const f32x4*)(feats + (size_t)u * DIN + col);
    }
    f32x4 acc = acc0 + acc1;
    unsigned short* xr = X + (size_t)n * KDIM;
    ushort4 hv;
    hv.x = f2bf(acc[0]); hv.y = f2bf(acc[1]); hv.z = f2bf(acc[2]); hv.w = f2bf(acc[3]);
    *(ushort4*)(xr + col) = hv;
    f32x4 sf = *(const f32x4*)(feats + (size_t)n * DIN + col);
    ushort4 sv;
    sv.x = f2bf(sf[0]); sv.y = f2bf(sf[1]); sv.z = f2bf(sf[2]); sv.w = f2bf(sf[3]);
    *(ushort4*)(xr + DIN + col) = sv;
}

// ---------- weights -> Wt[d][n][k] bf16 (transposed, K contiguous) ----------
__global__ __launch_bounds__(256)
void k_wt(const float* __restrict__ Wl, const float* __restrict__ Wr,
          unsigned short* __restrict__ Wt) {
    __shared__ float tile[32][33];
    int d = blockIdx.z, n0 = blockIdx.y * 32, k0 = blockIdx.x * 32;
    int t = threadIdx.x;
    int c = t & 31, r0 = t >> 5;   // r0 in 0..7
    const float* srcp = (k0 < DIN) ? (Wl + (size_t)d * DIN * DOUT)
                                   : (Wr + (size_t)d * DIN * DOUT - (size_t)DIN * DOUT);
    for (int rr = 0; rr < 4; ++rr) {
        int r = r0 + rr * 8;
        tile[r][c] = srcp[(size_t)(k0 + r) * DOUT + n0 + c];
    }
    __syncthreads();
    for (int rr = 0; rr < 4; ++rr) {
        int r = r0 + rr * 8;   // row in n
        Wt[((size_t)d * DOUT + n0 + r) * KDIM + k0 + c] = f2bf(tile[c][r]);
    }
}

// ---------- bucketed MFMA GEMM, 128x128 tiles + fused BN partial stats ----------
__global__ __launch_bounds__(256)
void k_gemm(const unsigned short* __restrict__ X, const unsigned short* __restrict__ Wt,
            const int2* __restrict__ tiles, const int* __restrict__ tile_cnt,
            const int* __restrict__ bucket_nodes, const int* __restrict__ bucket_cnt,
            const float* __restrict__ bl, float* __restrict__ out_pre,
            float* __restrict__ bn_sum, float* __restrict__ bn_sumsq) {
    if ((int)blockIdx.x >= *tile_cnt) return;
    int2 td = tiles[blockIdx.x];
    int d = td.x, m0 = td.y;
    int cnt = bucket_cnt[d];
    int n0 = blockIdx.y * 128;

    __shared__ __align__(16) unsigned short As[128 * 32];  // [row][k] 64B rows, unpadded
    __shared__ __align__(16) unsigned short Bs[128 * 32];
    __shared__ int ridS[128];
    __shared__ float colsum[128], colsq[128];

    int t = threadIdx.x;
    if (t < 128) {
        int gm = m0 + t;
        ridS[t] = (gm < cnt) ? bucket_nodes[d * N_NODES + gm] : -1;
        colsum[t] = 0.f; colsq[t] = 0.f;
    }
    __syncthreads();

    int lane = t & 63, w = t >> 6;
    int rrow = lane >> 2;          // 0..15
    int seg = lane & 3;

    // staging sources (2 chunks of 16 rows per wave per matrix)
    int rA0 = ridS[w * 32 + rrow];
    int rA1 = ridS[w * 32 + 16 + rrow];
    const unsigned short* gA0 = X + (size_t)max(rA0, 0) * KDIM + seg * 8;
    const unsigned short* gA1 = X + (size_t)max(rA1, 0) * KDIM + seg * 8;
    const unsigned short* gB0 = Wt + ((size_t)d * DOUT + n0 + w * 32 + rrow) * KDIM + seg * 8;
    const unsigned short* gB1 = gB0 + (size_t)16 * KDIM;
    unsigned short* lA0 = &As[(w * 32) * 32];
    unsigned short* lA1 = &As[(w * 32 + 16) * 32];
    unsigned short* lB0 = &Bs[(w * 32) * 32];
    unsigned short* lB1 = &Bs[(w * 32 + 16) * 32];

    // compute mapping: 4 waves in 2x2, each owns 64x64
    int wm = (w & 1) * 64, wn = (w >> 1) * 64;
    int lm = lane & 15, q = lane >> 4;

    f32x4 acc[4][4];
#pragma unroll
    for (int i = 0; i < 4; ++i)
#pragma unroll
        for (int j = 0; j < 4; ++j) acc[i][j] = (f32x4){0, 0, 0, 0};

    for (int kt = 0; kt < KDIM / 32; ++kt) {
        gload_lds16(gA0 + kt * 32, lA0);
        gload_lds16(gA1 + kt * 32, lA1);
        gload_lds16(gB0 + kt * 32, lB0);
        gload_lds16(gB1 + kt * 32, lB1);
        __syncthreads();

        bf16x8 af[4], bf[4];
#pragma unroll
        for (int mt = 0; mt < 4; ++mt)
            af[mt] = *(bf16x8*)&As[(wm + mt * 16 + lm) * 32 + q * 8];
#pragma unroll
        for (int nt = 0; nt < 4; ++nt)
            bf[nt] = *(bf16x8*)&Bs[(wn + nt * 16 + lm) * 32 + q * 8];
#pragma unroll
        for (int mt = 0; mt < 4; ++mt)
#pragma unroll
            for (int nt = 0; nt < 4; ++nt)
                acc[mt][nt] = __builtin_amdgcn_mfma_f32_16x16x32_bf16(af[mt], bf[nt], acc[mt][nt], 0, 0, 0);
        __syncthreads();
    }

    // epilogue: bias add + store + BN partial stats
    const float* blr = bl + d * DOUT + n0;
    float vsum[4] = {0, 0, 0, 0}, vsq[4] = {0, 0, 0, 0};
#pragma unroll
    for (int mt = 0; mt < 4; ++mt) {
#pragma unroll
        for (int r = 0; r < 4; ++r) {
            int row = wm + mt * 16 + q * 4 + r;
            int grow = ridS[row];
            if (grow < 0) continue;
            float* orow = out_pre + (size_t)grow * DOUT + n0;
#pragma unroll
            for (int nt = 0; nt < 4; ++nt) {
                int col = wn + nt * 16 + lm;
                float v = acc[mt][nt][r] + blr[col];
                orow[col] = v;
                vsum[nt] += v; vsq[nt] += v * v;
            }
        }
    }
#pragma unroll
    for (int nt = 0; nt < 4; ++nt) {
        vsum[nt] += __shfl_xor(vsum[nt], 16, 64);
        vsum[nt] += __shfl_xor(vsum[nt], 32, 64);
        vsq[nt]  += __shfl_xor(vsq[nt], 16, 64);
        vsq[nt]  += __shfl_xor(vsq[nt], 32, 64);
    }
    if (q == 0) {
#pragma unroll
        for (int nt = 0; nt < 4; ++nt) {
            atomicAdd(&colsum[wn + nt * 16 + lm], vsum[nt]);
            atomicAdd(&colsq[wn + nt * 16 + lm], vsq[nt]);
        }
    }
    __syncthreads();
    if (t < 128) {
        atomicAdd(&bn_sum[n0 + t], colsum[t]);
        atomicAdd(&bn_sumsq[n0 + t], colsq[t]);
    }
}

__global__ void k_bnfinal(const float* __restrict__ bn_sum, const float* __restrict__ bn_sumsq,
                          const float* __restrict__ gamma, const float* __restrict__ beta,
                          float* __restrict__ scale, float* __restrict__ shift) {
    int c = blockIdx.x * 256 + threadIdx.x;
    if (c >= DOUT) return;
    float mean = bn_sum[c] / (float)N_NODES;
    float var = bn_sumsq[c] / (float)N_NODES - mean * mean;
    float rs = rsqrtf(var + 1e-5f);
    float sc = gamma[c] * rs;
    scale[c] = sc;
    shift[c] = beta[c] - mean * sc;
}

// ---------- fused BN-apply + segment_max over in-neighbors + self ----------
__global__ __launch_bounds__(128)
void k_max(const float* __restrict__ out_pre, const int* __restrict__ eidx,
           const int* __restrict__ offsets, const float* __restrict__ scale,
           const float* __restrict__ shift, float* __restrict__ out) {
    int n = blockIdx.x;
    int col = threadIdx.x * 4;
    f32x4 sc = *(const f32x4*)(scale + col);
    f32x4 sh = *(const f32x4*)(shift + col);
    f32x4 mx = *(const f32x4*)(out_pre + (size_t)n * DOUT + col);
    int s = offsets[n], e = offsets[n + 1];
    int i = s;
    for (; i + 1 < e; i += 2) {
        int u0 = eidx[i], u1 = eidx[i + 1];
        f32x4 a = *(const f32x4*)(out_pre + (size_t)u0 * DOUT + col);
        f32x4 b = *(const f32x4*)(out_pre + (size_t)u1 * DOUT + col);
        mx[0] = fmaxf(mx[0], fmaxf(a[0], b[0]));
        mx[1] = fmaxf(mx[1], fmaxf(a[1], b[1]));
        mx[2] = fmaxf(mx[2], fmaxf(a[2], b[2]));
        mx[3] = fmaxf(mx[3], fmaxf(a[3], b[3]));
    }
    if (i < e) {
        int u = eidx[i];
        f32x4 a = *(const f32x4*)(out_pre + (size_t)u * DOUT + col);
        mx[0] = fmaxf(mx[0], a[0]);
        mx[1] = fmaxf(mx[1], a[1]);
        mx[2] = fmaxf(mx[2], a[2]);
        mx[3] = fmaxf(mx[3], a[3]);
    }
    f32x4 res = mx * sc + sh;
    *(f32x4*)(out + (size_t)n * DOUT + col) = res;
}

extern "C" void kernel_launch(void* const* d_in, const int* in_sizes, int n_in,
                              void* d_out, int out_size, void* d_ws, size_t ws_size,
                              hipStream_t stream) {
    const float* feats = (const float*)d_in[0];
    const int*   src   = (const int*)d_in[1];
    const int*   dst   = (const int*)d_in[2];
    const float* Wl    = (const float*)d_in[3];
    const float* Wr    = (const float*)d_in[4];
    const float* bl    = (const float*)d_in[5];
    const float* gamma = (const float*)d_in[6];
    const float* beta  = (const float*)d_in[7];
    float* out = (float*)d_out;

    char* ws = (char*)d_ws;
    size_t off = 0;
    auto alloc = [&](size_t bytes) -> void* {
        off = (off + 255) & ~(size_t)255;
        void* p = ws + off;
        off += bytes;
        return p;
    };

    // zero-initialized region (contiguous & first)
    int*   deg        = (int*)alloc(N_NODES * 4);
    int*   cursor     = (int*)alloc(N_NODES * 4);
    int*   bucket_cnt = (int*)alloc(16 * 4);
    float* bn_sum     = (float*)alloc(DOUT * 4);
    float* bn_sumsq   = (float*)alloc(DOUT * 4);
    size_t zbytes = off;

    int* offsets      = (int*)alloc((N_NODES + 1) * 4);
    int* bucket_nodes = (int*)alloc((size_t)NBUCKET * N_NODES * 4);
    int* eidx         = (int*)alloc(N_EDGES * 4);
    int2* tiles       = (int2*)alloc(MAXTILES * 8);
    int* tile_cnt     = (int*)alloc(4);
    float* scale      = (float*)alloc(DOUT * 4);
    float* shift      = (float*)alloc(DOUT * 4);
    unsigned short* X  = (unsigned short*)alloc((size_t)N_NODES * KDIM * 2);
    unsigned short* Wt = (unsigned short*)alloc((size_t)NBUCKET * DOUT * KDIM * 2);
    float* out_pre     = (float*)alloc((size_t)N_NODES * DOUT * 4);

    hipMemsetAsync(d_ws, 0, zbytes, stream);

    k_deg<<<(N_EDGES + 255) / 256, 256, 0, stream>>>(dst, deg);
    k_scan<<<1, 1024, 0, stream>>>(deg, offsets);
    k_bucket<<<(N_NODES + 255) / 256, 256, 0, stream>>>(deg, bucket_cnt, bucket_nodes);
    k_tiles<<<1, 64, 0, stream>>>(bucket_cnt, tiles, tile_cnt);
    k_scatter<<<(N_EDGES + 255) / 256, 256, 0, stream>>>(src, dst, offsets, cursor, eidx);
    k_build_x<<<N_NODES, 128, 0, stream>>>(feats, eidx, offsets, X);
    k_wt<<<dim3(KDIM / 32, DOUT / 32, NBUCKET), 256, 0, stream>>>(Wl, Wr, Wt);
    k_gemm<<<dim3(MAXTILES, 4), 256, 0, stream>>>(
        X, Wt, tiles, tile_cnt, bucket_nodes, bucket_cnt, bl, out_pre, bn_sum, bn_sumsq);
    k_bnfinal<<<2, 256, 0, stream>>>(bn_sum, bn_sumsq, gamma, beta, scale, shift);
    k_max<<<N_NODES, 128, 0, stream>>>(out_pre, eidx, offsets, scale, shift, out);
}

// Round 3
// 308.988 us; speedup vs baseline: 1.4431x; 1.2816x over previous
//
#include <hip/hip_runtime.h>
#include <hip/hip_bf16.h>
#include <stdint.h>

#define N_NODES 20000
#define N_EDGES 160000
#define DIN 512
#define DOUT 512
#define NBUCKET 11
#define KDIM 1024   // [h | feats]
#define MAXTILES 168  // sum_d ceil(cnt_d/128) <= floor(20000/128)+11 = 167

typedef float f32x4 __attribute__((ext_vector_type(4)));
typedef __attribute__((ext_vector_type(8))) __bf16 bf16x8;

static __device__ __forceinline__ unsigned short f2bf(float f) {
    union { float f; unsigned u; } v; v.f = f;
    unsigned r = v.u + 0x7FFFu + ((v.u >> 16) & 1u);
    return (unsigned short)(r >> 16);
}

static __device__ __forceinline__ void gload_lds16(const unsigned short* g, unsigned short* l) {
    __builtin_amdgcn_global_load_lds(
        (const __attribute__((address_space(1))) unsigned int*)g,
        (__attribute__((address_space(3))) unsigned int*)l, 16, 0, 0);
}

// ---------- CSR build ----------
__global__ void k_deg(const int* __restrict__ dst, int* __restrict__ deg) {
    int e = blockIdx.x * 256 + threadIdx.x;
    if (e < N_EDGES) atomicAdd(&deg[dst[e]], 1);
}

__global__ void k_scan(const int* __restrict__ deg, int* __restrict__ offsets) {
    __shared__ int part[1024];
    int t = threadIdx.x;
    const int CH = 20;   // 1024*20 >= 20000
    int s0 = t * CH, s1 = min(s0 + CH, N_NODES);
    int s = 0;
    for (int i = s0; i < s1; ++i) s += deg[i];
    part[t] = s; __syncthreads();
    for (int off = 1; off < 1024; off <<= 1) {
        int v = part[t];
        int a = (t >= off) ? part[t - off] : 0;
        __syncthreads();
        part[t] = v + a;
        __syncthreads();
    }
    int base = (t == 0) ? 0 : part[t - 1];
    for (int i = s0; i < s1; ++i) { offsets[i] = base; base += deg[i]; }
    if (t == 1023) offsets[N_NODES] = part[1023];
}

// two-phase counting sort: LDS histogram -> 11 global atomics/block -> scatter
__global__ __launch_bounds__(256)
void k_bucket(const int* __restrict__ deg, int* __restrict__ bucket_cnt,
              int* __restrict__ bucket_nodes) {
    __shared__ int lhist[NBUCKET];
    __shared__ int lbase[NBUCKET];
    int t = threadIdx.x;
    if (t < NBUCKET) lhist[t] = 0;
    __syncthreads();
    int v = blockIdx.x * 256 + t;
    int d = -1, slot = 0;
    if (v < N_NODES) {
        d = min(deg[v], NBUCKET - 1);
        slot = atomicAdd(&lhist[d], 1);
    }
    __syncthreads();
    if (t < NBUCKET && lhist[t] > 0) lbase[t] = atomicAdd(&bucket_cnt[t], lhist[t]);
    __syncthreads();
    if (v < N_NODES) bucket_nodes[d * N_NODES + lbase[d] + slot] = v;
}

__global__ void k_tiles(const int* __restrict__ bucket_cnt, int2* __restrict__ tiles,
                        int* __restrict__ tile_cnt) {
    if (threadIdx.x != 0 || blockIdx.x != 0) return;
    int tc = 0;
    for (int d = 0; d < NBUCKET; ++d) {
        int c = bucket_cnt[d];
        for (int m0 = 0; m0 < c; m0 += 128) tiles[tc++] = make_int2(d, m0);
    }
    *tile_cnt = tc;
}

__global__ void k_scatter(const int* __restrict__ src, const int* __restrict__ dst,
                          const int* __restrict__ offsets, int* __restrict__ cursor,
                          int* __restrict__ eidx) {
    int e = blockIdx.x * 256 + threadIdx.x;
    if (e >= N_EDGES) return;
    int v = dst[e];
    int slot = atomicAdd(&cursor[v], 1);
    eidx[offsets[v] + slot] = src[e];
}

// ---------- X = [h | feats] in bf16 ----------
__global__ __launch_bounds__(128)
void k_build_x(const float* __restrict__ feats, const int* __restrict__ eidx,
               const int* __restrict__ offsets, unsigned short* __restrict__ X) {
    int n = blockIdx.x;
    int col = threadIdx.x * 4;
    int s = offsets[n], e = offsets[n + 1];
    f32x4 acc0 = {0.f, 0.f, 0.f, 0.f};
    f32x4 acc1 = {0.f, 0.f, 0.f, 0.f};
    int i = s;
    for (; i + 1 < e; i += 2) {
        int u0 = eidx[i], u1 = eidx[i + 1];
        f32x4 f0 = *(const f32x4*)(feats + (size_t)u0 * DIN + col);
        f32x4 f1 = *(const f32x4*)(feats + (size_t)u1 * DIN + col);
        acc0 += f0; acc1 += f1;
    }
    if (i < e) {
        int u = eidx[i];
        acc0 += *(const f32x4*)(feats + (size_t)u * DIN + col);
    }
    f32x4 acc = acc0 + acc1;
    unsigned short* xr = X + (size_t)n * KDIM;
    ushort4 hv;
    hv.x = f2bf(acc[0]); hv.y = f2bf(acc[1]); hv.z = f2bf(acc[2]); hv.w = f2bf(acc[3]);
    *(ushort4*)(xr + col) = hv;
    f32x4 sf = *(const f32x4*)(feats + (size_t)n * DIN + col);
    ushort4 sv;
    sv.x = f2bf(sf[0]); sv.y = f2bf(sf[1]); sv.z = f2bf(sf[2]); sv.w = f2bf(sf[3]);
    *(ushort4*)(xr + DIN + col) = sv;
}

// ---------- weights -> Wt[d][n][k] bf16 (transposed, K contiguous) ----------
__global__ __launch_bounds__(256)
void k_wt(const float* __restrict__ Wl, const float* __restrict__ Wr,
          unsigned short* __restrict__ Wt) {
    __shared__ float tile[32][33];
    int d = blockIdx.z, n0 = blockIdx.y * 32, k0 = blockIdx.x * 32;
    int t = threadIdx.x;
    int c = t & 31, r0 = t >> 5;   // r0 in 0..7
    const float* srcp = (k0 < DIN) ? (Wl + (size_t)d * DIN * DOUT)
                                   : (Wr + (size_t)d * DIN * DOUT - (size_t)DIN * DOUT);
    for (int rr = 0; rr < 4; ++rr) {
        int r = r0 + rr * 8;
        tile[r][c] = srcp[(size_t)(k0 + r) * DOUT + n0 + c];
    }
    __syncthreads();
    for (int rr = 0; rr < 4; ++rr) {
        int r = r0 + rr * 8;   // row in n
        Wt[((size_t)d * DOUT + n0 + r) * KDIM + k0 + c] = f2bf(tile[c][r]);
    }
}

// ---------- bucketed MFMA GEMM, 128x128 tiles + fused BN partial stats ----------
__global__ __launch_bounds__(256)
void k_gemm(const unsigned short* __restrict__ X, const unsigned short* __restrict__ Wt,
            const int2* __restrict__ tiles, const int* __restrict__ tile_cnt,
            const int* __restrict__ bucket_nodes, const int* __restrict__ bucket_cnt,
            const float* __restrict__ bl, float* __restrict__ out_pre,
            float* __restrict__ bn_sum, float* __restrict__ bn_sumsq) {
    if ((int)blockIdx.x >= *tile_cnt) return;
    int2 td = tiles[blockIdx.x];
    int d = td.x, m0 = td.y;
    int cnt = bucket_cnt[d];
    int n0 = blockIdx.y * 128;

    __shared__ __align__(16) unsigned short As[128 * 32];  // [row][k] 64B rows, unpadded
    __shared__ __align__(16) unsigned short Bs[128 * 32];
    __shared__ int ridS[128];
    __shared__ float colsum[128], colsq[128];

    int t = threadIdx.x;
    if (t < 128) {
        int gm = m0 + t;
        ridS[t] = (gm < cnt) ? bucket_nodes[d * N_NODES + gm] : -1;
        colsum[t] = 0.f; colsq[t] = 0.f;
    }
    __syncthreads();

    int lane = t & 63, w = t >> 6;
    int rrow = lane >> 2;          // 0..15
    int seg = lane & 3;

    // staging sources (2 chunks of 16 rows per wave per matrix)
    int rA0 = ridS[w * 32 + rrow];
    int rA1 = ridS[w * 32 + 16 + rrow];
    const unsigned short* gA0 = X + (size_t)max(rA0, 0) * KDIM + seg * 8;
    const unsigned short* gA1 = X + (size_t)max(rA1, 0) * KDIM + seg * 8;
    const unsigned short* gB0 = Wt + ((size_t)d * DOUT + n0 + w * 32 + rrow) * KDIM + seg * 8;
    const unsigned short* gB1 = gB0 + (size_t)16 * KDIM;
    unsigned short* lA0 = &As[(w * 32) * 32];
    unsigned short* lA1 = &As[(w * 32 + 16) * 32];
    unsigned short* lB0 = &Bs[(w * 32) * 32];
    unsigned short* lB1 = &Bs[(w * 32 + 16) * 32];

    // compute mapping: 4 waves in 2x2, each owns 64x64
    int wm = (w & 1) * 64, wn = (w >> 1) * 64;
    int lm = lane & 15, q = lane >> 4;

    f32x4 acc[4][4];
#pragma unroll
    for (int i = 0; i < 4; ++i)
#pragma unroll
        for (int j = 0; j < 4; ++j) acc[i][j] = (f32x4){0, 0, 0, 0};

    for (int kt = 0; kt < KDIM / 32; ++kt) {
        gload_lds16(gA0 + kt * 32, lA0);
        gload_lds16(gA1 + kt * 32, lA1);
        gload_lds16(gB0 + kt * 32, lB0);
        gload_lds16(gB1 + kt * 32, lB1);
        __syncthreads();

        bf16x8 af[4], bf[4];
#pragma unroll
        for (int mt = 0; mt < 4; ++mt)
            af[mt] = *(bf16x8*)&As[(wm + mt * 16 + lm) * 32 + q * 8];
#pragma unroll
        for (int nt = 0; nt < 4; ++nt)
            bf[nt] = *(bf16x8*)&Bs[(wn + nt * 16 + lm) * 32 + q * 8];
#pragma unroll
        for (int mt = 0; mt < 4; ++mt)
#pragma unroll
            for (int nt = 0; nt < 4; ++nt)
                acc[mt][nt] = __builtin_amdgcn_mfma_f32_16x16x32_bf16(af[mt], bf[nt], acc[mt][nt], 0, 0, 0);
        __syncthreads();
    }

    // epilogue: bias add + store + BN partial stats
    const float* blr = bl + d * DOUT + n0;
    float vsum[4] = {0, 0, 0, 0}, vsq[4] = {0, 0, 0, 0};
#pragma unroll
    for (int mt = 0; mt < 4; ++mt) {
#pragma unroll
        for (int r = 0; r < 4; ++r) {
            int row = wm + mt * 16 + q * 4 + r;
            int grow = ridS[row];
            if (grow < 0) continue;
            float* orow = out_pre + (size_t)grow * DOUT + n0;
#pragma unroll
            for (int nt = 0; nt < 4; ++nt) {
                int col = wn + nt * 16 + lm;
                float v = acc[mt][nt][r] + blr[col];
                orow[col] = v;
                vsum[nt] += v; vsq[nt] += v * v;
            }
        }
    }
#pragma unroll
    for (int nt = 0; nt < 4; ++nt) {
        vsum[nt] += __shfl_xor(vsum[nt], 16, 64);
        vsum[nt] += __shfl_xor(vsum[nt], 32, 64);
        vsq[nt]  += __shfl_xor(vsq[nt], 16, 64);
        vsq[nt]  += __shfl_xor(vsq[nt], 32, 64);
    }
    if (q == 0) {
#pragma unroll
        for (int nt = 0; nt < 4; ++nt) {
            atomicAdd(&colsum[wn + nt * 16 + lm], vsum[nt]);
            atomicAdd(&colsq[wn + nt * 16 + lm], vsq[nt]);
        }
    }
    __syncthreads();
    if (t < 128) {
        atomicAdd(&bn_sum[n0 + t], colsum[t]);
        atomicAdd(&bn_sumsq[n0 + t], colsq[t]);
    }
}

__global__ void k_bnfinal(const float* __restrict__ bn_sum, const float* __restrict__ bn_sumsq,
                          const float* __restrict__ gamma, const float* __restrict__ beta,
                          float* __restrict__ scale, float* __restrict__ shift) {
    int c = blockIdx.x * 256 + threadIdx.x;
    if (c >= DOUT) return;
    float mean = bn_sum[c] / (float)N_NODES;
    float var = bn_sumsq[c] / (float)N_NODES - mean * mean;
    float rs = rsqrtf(var + 1e-5f);
    float sc = gamma[c] * rs;
    scale[c] = sc;
    shift[c] = beta[c] - mean * sc;
}

// ---------- fused BN-apply + segment_max over in-neighbors + self ----------
__global__ __launch_bounds__(128)
void k_max(const float* __restrict__ out_pre, const int* __restrict__ eidx,
           const int* __restrict__ offsets, const float* __restrict__ scale,
           const float* __restrict__ shift, float* __restrict__ out) {
    int n = blockIdx.x;
    int col = threadIdx.x * 4;
    f32x4 sc = *(const f32x4*)(scale + col);
    f32x4 sh = *(const f32x4*)(shift + col);
    f32x4 mx = *(const f32x4*)(out_pre + (size_t)n * DOUT + col);
    int s = offsets[n], e = offsets[n + 1];
    int i = s;
    for (; i + 1 < e; i += 2) {
        int u0 = eidx[i], u1 = eidx[i + 1];
        f32x4 a = *(const f32x4*)(out_pre + (size_t)u0 * DOUT + col);
        f32x4 b = *(const f32x4*)(out_pre + (size_t)u1 * DOUT + col);
        mx[0] = fmaxf(mx[0], fmaxf(a[0], b[0]));
        mx[1] = fmaxf(mx[1], fmaxf(a[1], b[1]));
        mx[2] = fmaxf(mx[2], fmaxf(a[2], b[2]));
        mx[3] = fmaxf(mx[3], fmaxf(a[3], b[3]));
    }
    if (i < e) {
        int u = eidx[i];
        f32x4 a = *(const f32x4*)(out_pre + (size_t)u * DOUT + col);
        mx[0] = fmaxf(mx[0], a[0]);
        mx[1] = fmaxf(mx[1], a[1]);
        mx[2] = fmaxf(mx[2], a[2]);
        mx[3] = fmaxf(mx[3], a[3]);
    }
    f32x4 res = mx * sc + sh;
    *(f32x4*)(out + (size_t)n * DOUT + col) = res;
}

extern "C" void kernel_launch(void* const* d_in, const int* in_sizes, int n_in,
                              void* d_out, int out_size, void* d_ws, size_t ws_size,
                              hipStream_t stream) {
    const float* feats = (const float*)d_in[0];
    const int*   src   = (const int*)d_in[1];
    const int*   dst   = (const int*)d_in[2];
    const float* Wl    = (const float*)d_in[3];
    const float* Wr    = (const float*)d_in[4];
    const float* bl    = (const float*)d_in[5];
    const float* gamma = (const float*)d_in[6];
    const float* beta  = (const float*)d_in[7];
    float* out = (float*)d_out;

    char* ws = (char*)d_ws;
    size_t off = 0;
    auto alloc = [&](size_t bytes) -> void* {
        off = (off + 255) & ~(size_t)255;
        void* p = ws + off;
        off += bytes;
        return p;
    };

    // zero-initialized region (contiguous & first)
    int*   deg        = (int*)alloc(N_NODES * 4);
    int*   cursor     = (int*)alloc(N_NODES * 4);
    int*   bucket_cnt = (int*)alloc(16 * 4);
    float* bn_sum     = (float*)alloc(DOUT * 4);
    float* bn_sumsq   = (float*)alloc(DOUT * 4);
    size_t zbytes = off;

    int* offsets      = (int*)alloc((N_NODES + 1) * 4);
    int* bucket_nodes = (int*)alloc((size_t)NBUCKET * N_NODES * 4);
    int* eidx         = (int*)alloc(N_EDGES * 4);
    int2* tiles       = (int2*)alloc(MAXTILES * 8);
    int* tile_cnt     = (int*)alloc(4);
    float* scale      = (float*)alloc(DOUT * 4);
    float* shift      = (float*)alloc(DOUT * 4);
    unsigned short* X  = (unsigned short*)alloc((size_t)N_NODES * KDIM * 2);
    unsigned short* Wt = (unsigned short*)alloc((size_t)NBUCKET * DOUT * KDIM * 2);
    float* out_pre     = (float*)alloc((size_t)N_NODES * DOUT * 4);

    hipMemsetAsync(d_ws, 0, zbytes, stream);

    k_deg<<<(N_EDGES + 255) / 256, 256, 0, stream>>>(dst, deg);
    k_scan<<<1, 1024, 0, stream>>>(deg, offsets);
    k_bucket<<<(N_NODES + 255) / 256, 256, 0, stream>>>(deg, bucket_cnt, bucket_nodes);
    k_tiles<<<1, 64, 0, stream>>>(bucket_cnt, tiles, tile_cnt);
    k_scatter<<<(N_EDGES + 255) / 256, 256, 0, stream>>>(src, dst, offsets, cursor, eidx);
    k_build_x<<<N_NODES, 128, 0, stream>>>(feats, eidx, offsets, X);
    k_wt<<<dim3(KDIM / 32, DOUT / 32, NBUCKET), 256, 0, stream>>>(Wl, Wr, Wt);
    k_gemm<<<dim3(MAXTILES, 4), 256, 0, stream>>>(
        X, Wt, tiles, tile_cnt, bucket_nodes, bucket_cnt, bl, out_pre, bn_sum, bn_sumsq);
    k_bnfinal<<<2, 256, 0, stream>>>(bn_sum, bn_sumsq, gamma, beta, scale, shift);
    k_max<<<N_NODES, 128, 0, stream>>>(out_pre, eidx, offsets, scale, shift, out);
}

// Round 4
// 268.881 us; speedup vs baseline: 1.6583x; 1.1492x over previous
//
#include <hip/hip_runtime.h>
#include <hip/hip_bf16.h>
#include <stdint.h>

#define N_NODES 20000
#define N_EDGES 160000
#define DIN 512
#define DOUT 512
#define NBUCKET 11
#define KDIM 1024   // [h | feats]
#define MAXTILES 168

typedef float f32x4 __attribute__((ext_vector_type(4)));
typedef __attribute__((ext_vector_type(8))) __bf16 bf16x8;

static __device__ __forceinline__ unsigned short f2bf(float f) {
    union { float f; unsigned u; } v; v.f = f;
    unsigned r = v.u + 0x7FFFu + ((v.u >> 16) & 1u);
    return (unsigned short)(r >> 16);
}
static __device__ __forceinline__ float bflo(unsigned p) {   // low bf16 of packed pair
    union { unsigned u; float f; } v; v.u = p << 16; return v.f;
}
static __device__ __forceinline__ float bfhi(unsigned p) {   // high bf16 of packed pair
    union { unsigned u; float f; } v; v.u = p & 0xFFFF0000u; return v.f;
}
static __device__ __forceinline__ unsigned packbf(float lo, float hi) {
    return (unsigned)f2bf(lo) | ((unsigned)f2bf(hi) << 16);
}

static __device__ __forceinline__ void gload_lds16(const unsigned short* g, unsigned short* l) {
    __builtin_amdgcn_global_load_lds(
        (const __attribute__((address_space(1))) unsigned int*)g,
        (__attribute__((address_space(3))) unsigned int*)l, 16, 0, 0);
}

// ---------- CSR build ----------
__global__ void k_deg(const int* __restrict__ dst, int* __restrict__ deg) {
    int e = blockIdx.x * 256 + threadIdx.x;
    if (e < N_EDGES) atomicAdd(&deg[dst[e]], 1);
}

__global__ void k_scan(const int* __restrict__ deg, int* __restrict__ offsets) {
    __shared__ int part[1024];
    int t = threadIdx.x;
    const int CH = 20;
    int s0 = t * CH, s1 = min(s0 + CH, N_NODES);
    int s = 0;
    for (int i = s0; i < s1; ++i) s += deg[i];
    part[t] = s; __syncthreads();
    for (int off = 1; off < 1024; off <<= 1) {
        int v = part[t];
        int a = (t >= off) ? part[t - off] : 0;
        __syncthreads();
        part[t] = v + a;
        __syncthreads();
    }
    int base = (t == 0) ? 0 : part[t - 1];
    for (int i = s0; i < s1; ++i) { offsets[i] = base; base += deg[i]; }
    if (t == 1023) offsets[N_NODES] = part[1023];
}

// two-phase counting sort: LDS histogram -> 11 global atomics/block -> scatter
__global__ __launch_bounds__(256)
void k_bucket(const int* __restrict__ deg, int* __restrict__ bucket_cnt,
              int* __restrict__ bucket_nodes) {
    __shared__ int lhist[NBUCKET];
    __shared__ int lbase[NBUCKET];
    int t = threadIdx.x;
    if (t < NBUCKET) lhist[t] = 0;
    __syncthreads();
    int v = blockIdx.x * 256 + t;
    int d = -1, slot = 0;
    if (v < N_NODES) {
        d = min(deg[v], NBUCKET - 1);
        slot = atomicAdd(&lhist[d], 1);
    }
    __syncthreads();
    if (t < NBUCKET && lhist[t] > 0) lbase[t] = atomicAdd(&bucket_cnt[t], lhist[t]);
    __syncthreads();
    if (v < N_NODES) bucket_nodes[d * N_NODES + lbase[d] + slot] = v;
}

__global__ void k_tiles(const int* __restrict__ bucket_cnt, int2* __restrict__ tiles,
                        int* __restrict__ tile_cnt) {
    if (threadIdx.x != 0 || blockIdx.x != 0) return;
    int tc = 0;
    for (int d = 0; d < NBUCKET; ++d) {
        int c = bucket_cnt[d];
        for (int m0 = 0; m0 < c; m0 += 128) tiles[tc++] = make_int2(d, m0);
    }
    *tile_cnt = tc;
}

__global__ void k_scatter(const int* __restrict__ src, const int* __restrict__ dst,
                          const int* __restrict__ offsets, int* __restrict__ cursor,
                          int* __restrict__ eidx) {
    int e = blockIdx.x * 256 + threadIdx.x;
    if (e >= N_EDGES) return;
    int v = dst[e];
    int slot = atomicAdd(&cursor[v], 1);
    eidx[offsets[v] + slot] = src[e];
}

// ---------- feats -> bf16 into X's feats-half ----------
__global__ __launch_bounds__(64)
void k_cast(const float* __restrict__ feats, unsigned short* __restrict__ X) {
    int n = blockIdx.x;
    int col = threadIdx.x * 8;
    f32x4 a = *(const f32x4*)(feats + (size_t)n * DIN + col);
    f32x4 b = *(const f32x4*)(feats + (size_t)n * DIN + col + 4);
    uint4 p;
    p.x = packbf(a[0], a[1]); p.y = packbf(a[2], a[3]);
    p.z = packbf(b[0], b[1]); p.w = packbf(b[2], b[3]);
    *(uint4*)(X + (size_t)n * KDIM + DIN + col) = p;
}

// ---------- h = sum of neighbor bf16 rows (gathered from X feats-half) ----------
__global__ __launch_bounds__(64)
void k_build_x(const int* __restrict__ eidx, const int* __restrict__ offsets,
               unsigned short* __restrict__ X) {
    int n = blockIdx.x;
    int col = threadIdx.x * 8;
    int s = offsets[n], e = offsets[n + 1];
    float acc[8] = {0, 0, 0, 0, 0, 0, 0, 0};
    for (int i = s; i < e; ++i) {
        int u = eidx[i];
        uint4 p = *(const uint4*)(X + (size_t)u * KDIM + DIN + col);
        acc[0] += bflo(p.x); acc[1] += bfhi(p.x);
        acc[2] += bflo(p.y); acc[3] += bfhi(p.y);
        acc[4] += bflo(p.z); acc[5] += bfhi(p.z);
        acc[6] += bflo(p.w); acc[7] += bfhi(p.w);
    }
    uint4 o;
    o.x = packbf(acc[0], acc[1]); o.y = packbf(acc[2], acc[3]);
    o.z = packbf(acc[4], acc[5]); o.w = packbf(acc[6], acc[7]);
    *(uint4*)(X + (size_t)n * KDIM + col) = o;
}

// ---------- weights -> Wt[d][n][k] bf16 (transposed, K contiguous) ----------
__global__ __launch_bounds__(256)
void k_wt(const float* __restrict__ Wl, const float* __restrict__ Wr,
          unsigned short* __restrict__ Wt) {
    __shared__ float tile[32][33];
    int d = blockIdx.z, n0 = blockIdx.y * 32, k0 = blockIdx.x * 32;
    int t = threadIdx.x;
    int c = t & 31, r0 = t >> 5;
    const float* srcp = (k0 < DIN) ? (Wl + (size_t)d * DIN * DOUT)
                                   : (Wr + (size_t)d * DIN * DOUT - (size_t)DIN * DOUT);
    for (int rr = 0; rr < 4; ++rr) {
        int r = r0 + rr * 8;
        tile[r][c] = srcp[(size_t)(k0 + r) * DOUT + n0 + c];
    }
    __syncthreads();
    for (int rr = 0; rr < 4; ++rr) {
        int r = r0 + rr * 8;
        Wt[((size_t)d * DOUT + n0 + r) * KDIM + k0 + c] = f2bf(tile[c][r]);
    }
}

// ---------- bucketed MFMA GEMM, 128x128 tiles + fused BN partial stats ----------
__global__ __launch_bounds__(256)
void k_gemm(const unsigned short* __restrict__ X, const unsigned short* __restrict__ Wt,
            const int2* __restrict__ tiles, const int* __restrict__ tile_cnt,
            const int* __restrict__ bucket_nodes, const int* __restrict__ bucket_cnt,
            const float* __restrict__ bl, unsigned short* __restrict__ out_pre,
            float* __restrict__ bn_sum, float* __restrict__ bn_sumsq) {
    if ((int)blockIdx.x >= *tile_cnt) return;
    int2 td = tiles[blockIdx.x];
    int d = td.x, m0 = td.y;
    int cnt = bucket_cnt[d];
    int n0 = blockIdx.y * 128;

    __shared__ __align__(16) unsigned short As[128 * 32];
    __shared__ __align__(16) unsigned short Bs[128 * 32];
    __shared__ int ridS[128];
    __shared__ float colsum[128], colsq[128];

    int t = threadIdx.x;
    if (t < 128) {
        int gm = m0 + t;
        ridS[t] = (gm < cnt) ? bucket_nodes[d * N_NODES + gm] : -1;
        colsum[t] = 0.f; colsq[t] = 0.f;
    }
    __syncthreads();

    int lane = t & 63, w = t >> 6;
    int rrow = lane >> 2;
    int seg = lane & 3;

    int rA0 = ridS[w * 32 + rrow];
    int rA1 = ridS[w * 32 + 16 + rrow];
    const unsigned short* gA0 = X + (size_t)max(rA0, 0) * KDIM + seg * 8;
    const unsigned short* gA1 = X + (size_t)max(rA1, 0) * KDIM + seg * 8;
    const unsigned short* gB0 = Wt + ((size_t)d * DOUT + n0 + w * 32 + rrow) * KDIM + seg * 8;
    const unsigned short* gB1 = gB0 + (size_t)16 * KDIM;
    unsigned short* lA0 = &As[(w * 32) * 32];
    unsigned short* lA1 = &As[(w * 32 + 16) * 32];
    unsigned short* lB0 = &Bs[(w * 32) * 32];
    unsigned short* lB1 = &Bs[(w * 32 + 16) * 32];

    int wm = (w & 1) * 64, wn = (w >> 1) * 64;
    int lm = lane & 15, q = lane >> 4;

    f32x4 acc[4][4];
#pragma unroll
    for (int i = 0; i < 4; ++i)
#pragma unroll
        for (int j = 0; j < 4; ++j) acc[i][j] = (f32x4){0, 0, 0, 0};

    for (int kt = 0; kt < KDIM / 32; ++kt) {
        gload_lds16(gA0 + kt * 32, lA0);
        gload_lds16(gA1 + kt * 32, lA1);
        gload_lds16(gB0 + kt * 32, lB0);
        gload_lds16(gB1 + kt * 32, lB1);
        __syncthreads();

        bf16x8 af[4], bf[4];
#pragma unroll
        for (int mt = 0; mt < 4; ++mt)
            af[mt] = *(bf16x8*)&As[(wm + mt * 16 + lm) * 32 + q * 8];
#pragma unroll
        for (int nt = 0; nt < 4; ++nt)
            bf[nt] = *(bf16x8*)&Bs[(wn + nt * 16 + lm) * 32 + q * 8];
#pragma unroll
        for (int mt = 0; mt < 4; ++mt)
#pragma unroll
            for (int nt = 0; nt < 4; ++nt)
                acc[mt][nt] = __builtin_amdgcn_mfma_f32_16x16x32_bf16(af[mt], bf[nt], acc[mt][nt], 0, 0, 0);
        __syncthreads();
    }

    const float* blr = bl + d * DOUT + n0;
    float vsum[4] = {0, 0, 0, 0}, vsq[4] = {0, 0, 0, 0};
#pragma unroll
    for (int mt = 0; mt < 4; ++mt) {
#pragma unroll
        for (int r = 0; r < 4; ++r) {
            int row = wm + mt * 16 + q * 4 + r;
            int grow = ridS[row];
            if (grow < 0) continue;
            unsigned short* orow = out_pre + (size_t)grow * DOUT + n0;
#pragma unroll
            for (int nt = 0; nt < 4; ++nt) {
                int col = wn + nt * 16 + lm;
                float v = acc[mt][nt][r] + blr[col];
                orow[col] = f2bf(v);
                vsum[nt] += v; vsq[nt] += v * v;
            }
        }
    }
#pragma unroll
    for (int nt = 0; nt < 4; ++nt) {
        vsum[nt] += __shfl_xor(vsum[nt], 16, 64);
        vsum[nt] += __shfl_xor(vsum[nt], 32, 64);
        vsq[nt]  += __shfl_xor(vsq[nt], 16, 64);
        vsq[nt]  += __shfl_xor(vsq[nt], 32, 64);
    }
    if (q == 0) {
#pragma unroll
        for (int nt = 0; nt < 4; ++nt) {
            atomicAdd(&colsum[wn + nt * 16 + lm], vsum[nt]);
            atomicAdd(&colsq[wn + nt * 16 + lm], vsq[nt]);
        }
    }
    __syncthreads();
    if (t < 128) {
        atomicAdd(&bn_sum[n0 + t], colsum[t]);
        atomicAdd(&bn_sumsq[n0 + t], colsq[t]);
    }
}

__global__ void k_bnfinal(const float* __restrict__ bn_sum, const float* __restrict__ bn_sumsq,
                          const float* __restrict__ gamma, const float* __restrict__ beta,
                          float* __restrict__ scale, float* __restrict__ shift) {
    int c = blockIdx.x * 256 + threadIdx.x;
    if (c >= DOUT) return;
    float mean = bn_sum[c] / (float)N_NODES;
    float var = bn_sumsq[c] / (float)N_NODES - mean * mean;
    float rs = rsqrtf(var + 1e-5f);
    float sc = gamma[c] * rs;
    scale[c] = sc;
    shift[c] = beta[c] - mean * sc;
}

// ---------- fused segment_max over bf16 rows + BN-apply ----------
__global__ __launch_bounds__(64)
void k_max(const unsigned short* __restrict__ out_pre, const int* __restrict__ eidx,
           const int* __restrict__ offsets, const float* __restrict__ scale,
           const float* __restrict__ shift, float* __restrict__ out) {
    int n = blockIdx.x;
    int col = threadIdx.x * 8;
    float mx[8];
    {
        uint4 p = *(const uint4*)(out_pre + (size_t)n * DOUT + col);
        mx[0] = bflo(p.x); mx[1] = bfhi(p.x);
        mx[2] = bflo(p.y); mx[3] = bfhi(p.y);
        mx[4] = bflo(p.z); mx[5] = bfhi(p.z);
        mx[6] = bflo(p.w); mx[7] = bfhi(p.w);
    }
    int s = offsets[n], e = offsets[n + 1];
    for (int i = s; i < e; ++i) {
        int u = eidx[i];
        uint4 p = *(const uint4*)(out_pre + (size_t)u * DOUT + col);
        mx[0] = fmaxf(mx[0], bflo(p.x)); mx[1] = fmaxf(mx[1], bfhi(p.x));
        mx[2] = fmaxf(mx[2], bflo(p.y)); mx[3] = fmaxf(mx[3], bfhi(p.y));
        mx[4] = fmaxf(mx[4], bflo(p.z)); mx[5] = fmaxf(mx[5], bfhi(p.z));
        mx[6] = fmaxf(mx[6], bflo(p.w)); mx[7] = fmaxf(mx[7], bfhi(p.w));
    }
    f32x4 sc0 = *(const f32x4*)(scale + col);
    f32x4 sc1 = *(const f32x4*)(scale + col + 4);
    f32x4 sh0 = *(const f32x4*)(shift + col);
    f32x4 sh1 = *(const f32x4*)(shift + col + 4);
    f32x4 r0, r1;
    r0[0] = mx[0] * sc0[0] + sh0[0]; r0[1] = mx[1] * sc0[1] + sh0[1];
    r0[2] = mx[2] * sc0[2] + sh0[2]; r0[3] = mx[3] * sc0[3] + sh0[3];
    r1[0] = mx[4] * sc1[0] + sh1[0]; r1[1] = mx[5] * sc1[1] + sh1[1];
    r1[2] = mx[6] * sc1[2] + sh1[2]; r1[3] = mx[7] * sc1[3] + sh1[3];
    *(f32x4*)(out + (size_t)n * DOUT + col) = r0;
    *(f32x4*)(out + (size_t)n * DOUT + col + 4) = r1;
}

extern "C" void kernel_launch(void* const* d_in, const int* in_sizes, int n_in,
                              void* d_out, int out_size, void* d_ws, size_t ws_size,
                              hipStream_t stream) {
    const float* feats = (const float*)d_in[0];
    const int*   src   = (const int*)d_in[1];
    const int*   dst   = (const int*)d_in[2];
    const float* Wl    = (const float*)d_in[3];
    const float* Wr    = (const float*)d_in[4];
    const float* bl    = (const float*)d_in[5];
    const float* gamma = (const float*)d_in[6];
    const float* beta  = (const float*)d_in[7];
    float* out = (float*)d_out;

    char* ws = (char*)d_ws;
    size_t off = 0;
    auto alloc = [&](size_t bytes) -> void* {
        off = (off + 255) & ~(size_t)255;
        void* p = ws + off;
        off += bytes;
        return p;
    };

    // zero-initialized region (contiguous & first)
    int*   deg        = (int*)alloc(N_NODES * 4);
    int*   cursor     = (int*)alloc(N_NODES * 4);
    int*   bucket_cnt = (int*)alloc(16 * 4);
    float* bn_sum     = (float*)alloc(DOUT * 4);
    float* bn_sumsq   = (float*)alloc(DOUT * 4);
    size_t zbytes = off;

    int* offsets      = (int*)alloc((N_NODES + 1) * 4);
    int* bucket_nodes = (int*)alloc((size_t)NBUCKET * N_NODES * 4);
    int* eidx         = (int*)alloc(N_EDGES * 4);
    int2* tiles       = (int2*)alloc(MAXTILES * 8);
    int* tile_cnt     = (int*)alloc(4);
    float* scale      = (float*)alloc(DOUT * 4);
    float* shift      = (float*)alloc(DOUT * 4);
    unsigned short* X  = (unsigned short*)alloc((size_t)N_NODES * KDIM * 2);
    unsigned short* Wt = (unsigned short*)alloc((size_t)NBUCKET * DOUT * KDIM * 2);
    unsigned short* out_pre = (unsigned short*)alloc((size_t)N_NODES * DOUT * 2);

    hipMemsetAsync(d_ws, 0, zbytes, stream);

    k_deg<<<(N_EDGES + 255) / 256, 256, 0, stream>>>(dst, deg);
    k_scan<<<1, 1024, 0, stream>>>(deg, offsets);
    k_bucket<<<(N_NODES + 255) / 256, 256, 0, stream>>>(deg, bucket_cnt, bucket_nodes);
    k_tiles<<<1, 64, 0, stream>>>(bucket_cnt, tiles, tile_cnt);
    k_scatter<<<(N_EDGES + 255) / 256, 256, 0, stream>>>(src, dst, offsets, cursor, eidx);
    k_cast<<<N_NODES, 64, 0, stream>>>(feats, X);
    k_build_x<<<N_NODES, 64, 0, stream>>>(eidx, offsets, X);
    k_wt<<<dim3(KDIM / 32, DOUT / 32, NBUCKET), 256, 0, stream>>>(Wl, Wr, Wt);
    k_gemm<<<dim3(MAXTILES, 4), 256, 0, stream>>>(
        X, Wt, tiles, tile_cnt, bucket_nodes, bucket_cnt, bl, out_pre, bn_sum, bn_sumsq);
    k_bnfinal<<<2, 256, 0, stream>>>(bn_sum, bn_sumsq, gamma, beta, scale, shift);
    k_max<<<N_NODES, 64, 0, stream>>>(out_pre, eidx, offsets, scale, shift, out);
}

// Round 5
// 261.663 us; speedup vs baseline: 1.7041x; 1.0276x over previous
//
#include <hip/hip_runtime.h>
#include <hip/hip_bf16.h>
#include <stdint.h>

#define N_NODES 20000
#define N_EDGES 160000
#define DIN 512
#define DOUT 512
#define NBUCKET 11
#define KDIM 1024   // [h | feats]
#define MAXTILES 168
#define BN_EPS 1e-5f
#define CAST_BLOCKS (N_NODES / 4)                  // 5000 (4 rows / 256-thr block)
#define WT_BLOCKS ((KDIM / 32) * (DOUT / 32) * NBUCKET)  // 5632

typedef float f32x4 __attribute__((ext_vector_type(4)));
typedef __attribute__((ext_vector_type(8))) __bf16 bf16x8;

static __device__ __forceinline__ unsigned short f2bf(float f) {
    union { float f; unsigned u; } v; v.f = f;
    unsigned r = v.u + 0x7FFFu + ((v.u >> 16) & 1u);
    return (unsigned short)(r >> 16);
}
static __device__ __forceinline__ float bflo(unsigned p) {
    union { unsigned u; float f; } v; v.u = p << 16; return v.f;
}
static __device__ __forceinline__ float bfhi(unsigned p) {
    union { unsigned u; float f; } v; v.u = p & 0xFFFF0000u; return v.f;
}
static __device__ __forceinline__ unsigned packbf(float lo, float hi) {
    return (unsigned)f2bf(lo) | ((unsigned)f2bf(hi) << 16);
}

static __device__ __forceinline__ void gload_lds16(const unsigned short* g, unsigned short* l) {
    __builtin_amdgcn_global_load_lds(
        (const __attribute__((address_space(1))) unsigned int*)g,
        (__attribute__((address_space(3))) unsigned int*)l, 16, 0, 0);
}

// ---------- CSR build ----------
__global__ void k_deg(const int* __restrict__ dst, int* __restrict__ deg) {
    int e = blockIdx.x * 256 + threadIdx.x;
    if (e < N_EDGES) atomicAdd(&deg[dst[e]], 1);
}

__global__ void k_scan(const int* __restrict__ deg, int* __restrict__ offsets) {
    __shared__ int part[1024];
    int t = threadIdx.x;
    const int CH = 20;
    int s0 = t * CH, s1 = min(s0 + CH, N_NODES);
    int s = 0;
    for (int i = s0; i < s1; ++i) s += deg[i];
    part[t] = s; __syncthreads();
    for (int off = 1; off < 1024; off <<= 1) {
        int v = part[t];
        int a = (t >= off) ? part[t - off] : 0;
        __syncthreads();
        part[t] = v + a;
        __syncthreads();
    }
    int base = (t == 0) ? 0 : part[t - 1];
    for (int i = s0; i < s1; ++i) { offsets[i] = base; base += deg[i]; }
    if (t == 1023) offsets[N_NODES] = part[1023];
}

__global__ __launch_bounds__(256)
void k_bucket(const int* __restrict__ deg, int* __restrict__ bucket_cnt,
              int* __restrict__ bucket_nodes) {
    __shared__ int lhist[NBUCKET];
    __shared__ int lbase[NBUCKET];
    int t = threadIdx.x;
    if (t < NBUCKET) lhist[t] = 0;
    __syncthreads();
    int v = blockIdx.x * 256 + t;
    int d = -1, slot = 0;
    if (v < N_NODES) {
        d = min(deg[v], NBUCKET - 1);
        slot = atomicAdd(&lhist[d], 1);
    }
    __syncthreads();
    if (t < NBUCKET && lhist[t] > 0) lbase[t] = atomicAdd(&bucket_cnt[t], lhist[t]);
    __syncthreads();
    if (v < N_NODES) bucket_nodes[d * N_NODES + lbase[d] + slot] = v;
}

__global__ void k_tiles(const int* __restrict__ bucket_cnt, int2* __restrict__ tiles,
                        int* __restrict__ tile_cnt) {
    if (threadIdx.x != 0 || blockIdx.x != 0) return;
    int tc = 0;
    for (int d = 0; d < NBUCKET; ++d) {
        int c = bucket_cnt[d];
        for (int m0 = 0; m0 < c; m0 += 128) tiles[tc++] = make_int2(d, m0);
    }
    *tile_cnt = tc;
}

__global__ void k_scatter(const int* __restrict__ src, const int* __restrict__ dst,
                          const int* __restrict__ offsets, int* __restrict__ cursor,
                          int* __restrict__ eidx) {
    int e = blockIdx.x * 256 + threadIdx.x;
    if (e >= N_EDGES) return;
    int v = dst[e];
    int slot = atomicAdd(&cursor[v], 1);
    eidx[offsets[v] + slot] = src[e];
}

// ---------- fused: feats->bf16 cast (X feats-half) + weight transpose ----------
__global__ __launch_bounds__(256)
void k_prep(const float* __restrict__ feats, const float* __restrict__ Wl,
            const float* __restrict__ Wr, unsigned short* __restrict__ X,
            unsigned short* __restrict__ Wt) {
    int b = blockIdx.x;
    int t = threadIdx.x;
    if (b < CAST_BLOCKS) {
        int n = b * 4 + (t >> 6);
        int col = (t & 63) * 8;
        f32x4 a = *(const f32x4*)(feats + (size_t)n * DIN + col);
        f32x4 c = *(const f32x4*)(feats + (size_t)n * DIN + col + 4);
        uint4 p;
        p.x = packbf(a[0], a[1]); p.y = packbf(a[2], a[3]);
        p.z = packbf(c[0], c[1]); p.w = packbf(c[2], c[3]);
        *(uint4*)(X + (size_t)n * KDIM + DIN + col) = p;
        return;
    }
    __shared__ float tile[32][33];
    int idx = b - CAST_BLOCKS;
    int d = idx / (32 * 16);
    int rem = idx % (32 * 16);
    int k0 = (rem & 31) * 32;
    int n0 = (rem >> 5) * 32;
    int c = t & 31, r0 = t >> 5;
    const float* srcp = (k0 < DIN) ? (Wl + (size_t)d * DIN * DOUT)
                                   : (Wr + (size_t)d * DIN * DOUT - (size_t)DIN * DOUT);
    for (int rr = 0; rr < 4; ++rr) {
        int r = r0 + rr * 8;
        tile[r][c] = srcp[(size_t)(k0 + r) * DOUT + n0 + c];
    }
    __syncthreads();
    for (int rr = 0; rr < 4; ++rr) {
        int r = r0 + rr * 8;
        Wt[((size_t)d * DOUT + n0 + r) * KDIM + k0 + c] = f2bf(tile[c][r]);
    }
}

// ---------- h = sum of neighbor bf16 rows ----------
__global__ __launch_bounds__(64)
void k_build_x(const int* __restrict__ eidx, const int* __restrict__ offsets,
               unsigned short* __restrict__ X) {
    int n = blockIdx.x;
    int col = threadIdx.x * 8;
    int s = offsets[n], e = offsets[n + 1];
    float a0[8] = {0,0,0,0,0,0,0,0}, a1[8] = {0,0,0,0,0,0,0,0};
    int i = s;
    for (; i + 1 < e; i += 2) {
        int u0 = eidx[i], u1 = eidx[i + 1];
        uint4 p = *(const uint4*)(X + (size_t)u0 * KDIM + DIN + col);
        uint4 q = *(const uint4*)(X + (size_t)u1 * KDIM + DIN + col);
        a0[0] += bflo(p.x); a0[1] += bfhi(p.x); a0[2] += bflo(p.y); a0[3] += bfhi(p.y);
        a0[4] += bflo(p.z); a0[5] += bfhi(p.z); a0[6] += bflo(p.w); a0[7] += bfhi(p.w);
        a1[0] += bflo(q.x); a1[1] += bfhi(q.x); a1[2] += bflo(q.y); a1[3] += bfhi(q.y);
        a1[4] += bflo(q.z); a1[5] += bfhi(q.z); a1[6] += bflo(q.w); a1[7] += bfhi(q.w);
    }
    if (i < e) {
        int u = eidx[i];
        uint4 p = *(const uint4*)(X + (size_t)u * KDIM + DIN + col);
        a0[0] += bflo(p.x); a0[1] += bfhi(p.x); a0[2] += bflo(p.y); a0[3] += bfhi(p.y);
        a0[4] += bflo(p.z); a0[5] += bfhi(p.z); a0[6] += bflo(p.w); a0[7] += bfhi(p.w);
    }
    uint4 o;
    o.x = packbf(a0[0] + a1[0], a0[1] + a1[1]);
    o.y = packbf(a0[2] + a1[2], a0[3] + a1[3]);
    o.z = packbf(a0[4] + a1[4], a0[5] + a1[5]);
    o.w = packbf(a0[6] + a1[6], a0[7] + a1[7]);
    *(uint4*)(X + (size_t)n * KDIM + col) = o;
}

// ---------- bucketed MFMA GEMM, 128x128 tile, BK=64, swizzled LDS ----------
__global__ __launch_bounds__(256)
void k_gemm(const unsigned short* __restrict__ X, const unsigned short* __restrict__ Wt,
            const int2* __restrict__ tiles, const int* __restrict__ tile_cnt,
            const int* __restrict__ bucket_nodes, const int* __restrict__ bucket_cnt,
            const float* __restrict__ bl, unsigned short* __restrict__ out_pre,
            float* __restrict__ bn_sum, float* __restrict__ bn_sumsq) {
    if ((int)blockIdx.x >= *tile_cnt) return;
    int2 td = tiles[blockIdx.x];
    int d = td.x, m0 = td.y;
    int cnt = bucket_cnt[d];
    int n0 = blockIdx.y * 128;

    // rows of 128B (=32 banks); slot p of row holds global k-segment p^(row&7)
    __shared__ __align__(16) unsigned short As[128 * 64];
    __shared__ __align__(16) unsigned short Bs[128 * 64];
    __shared__ int ridS[128];
    __shared__ float colsum[128], colsq[128];

    int t = threadIdx.x;
    if (t < 128) {
        int gm = m0 + t;
        ridS[t] = (gm < cnt) ? bucket_nodes[d * N_NODES + gm] : -1;
        colsum[t] = 0.f; colsq[t] = 0.f;
    }
    __syncthreads();

    int lane = t & 63, w = t >> 6;
    int r = lane >> 3;          // row within 8-row staging group
    int s = lane & 7;           // LDS slot
    int sg = s ^ r;             // swizzled global segment

    const unsigned short* gA[4];
    const unsigned short* gB[4];
    unsigned short* lA[4];
    unsigned short* lB[4];
#pragma unroll
    for (int j = 0; j < 4; ++j) {
        int row = w * 32 + j * 8 + r;
        int rid = max(ridS[row], 0);
        gA[j] = X + (size_t)rid * KDIM + sg * 8;
        gB[j] = Wt + ((size_t)d * DOUT + n0 + row) * KDIM + sg * 8;
        lA[j] = &As[(w * 32 + j * 8) * 64];
        lB[j] = &Bs[(w * 32 + j * 8) * 64];
    }

    int wm = (w & 1) * 64, wn = (w >> 1) * 64;
    int lm = lane & 15, q = lane >> 4;
    int sw = lm & 7;            // reader swizzle key

    f32x4 acc[4][4];
#pragma unroll
    for (int i = 0; i < 4; ++i)
#pragma unroll
        for (int j = 0; j < 4; ++j) acc[i][j] = (f32x4){0, 0, 0, 0};

    for (int kt = 0; kt < KDIM / 64; ++kt) {
#pragma unroll
        for (int j = 0; j < 4; ++j) {
            gload_lds16(gA[j] + kt * 64, lA[j]);
            gload_lds16(gB[j] + kt * 64, lB[j]);
        }
        __syncthreads();

#pragma unroll
        for (int kk = 0; kk < 2; ++kk) {
            int slot = (kk * 4 + q) ^ sw;
            bf16x8 af[4], bfr[4];
#pragma unroll
            for (int mt = 0; mt < 4; ++mt)
                af[mt] = *(bf16x8*)&As[(wm + mt * 16 + lm) * 64 + slot * 8];
#pragma unroll
            for (int nt = 0; nt < 4; ++nt)
                bfr[nt] = *(bf16x8*)&Bs[(wn + nt * 16 + lm) * 64 + slot * 8];
#pragma unroll
            for (int mt = 0; mt < 4; ++mt)
#pragma unroll
                for (int nt = 0; nt < 4; ++nt)
                    acc[mt][nt] = __builtin_amdgcn_mfma_f32_16x16x32_bf16(af[mt], bfr[nt], acc[mt][nt], 0, 0, 0);
        }
        __syncthreads();
    }

    const float* blr = bl + d * DOUT + n0;
    float vsum[4] = {0, 0, 0, 0}, vsq[4] = {0, 0, 0, 0};
#pragma unroll
    for (int mt = 0; mt < 4; ++mt) {
#pragma unroll
        for (int rr = 0; rr < 4; ++rr) {
            int row = wm + mt * 16 + q * 4 + rr;
            int grow = ridS[row];
            if (grow < 0) continue;
            unsigned short* orow = out_pre + (size_t)grow * DOUT + n0;
#pragma unroll
            for (int nt = 0; nt < 4; ++nt) {
                int col = wn + nt * 16 + lm;
                float v = acc[mt][nt][rr] + blr[col];
                orow[col] = f2bf(v);
                vsum[nt] += v; vsq[nt] += v * v;
            }
        }
    }
#pragma unroll
    for (int nt = 0; nt < 4; ++nt) {
        vsum[nt] += __shfl_xor(vsum[nt], 16, 64);
        vsum[nt] += __shfl_xor(vsum[nt], 32, 64);
        vsq[nt]  += __shfl_xor(vsq[nt], 16, 64);
        vsq[nt]  += __shfl_xor(vsq[nt], 32, 64);
    }
    if (q == 0) {
#pragma unroll
        for (int nt = 0; nt < 4; ++nt) {
            atomicAdd(&colsum[wn + nt * 16 + lm], vsum[nt]);
            atomicAdd(&colsq[wn + nt * 16 + lm], vsq[nt]);
        }
    }
    __syncthreads();
    if (t < 128) {
        atomicAdd(&bn_sum[n0 + t], colsum[t]);
        atomicAdd(&bn_sumsq[n0 + t], colsq[t]);
    }
}

// ---------- fused BN-final + segment_max + BN-apply ----------
__global__ __launch_bounds__(64)
void k_max(const unsigned short* __restrict__ out_pre, const int* __restrict__ eidx,
           const int* __restrict__ offsets, const float* __restrict__ bn_sum,
           const float* __restrict__ bn_sumsq, const float* __restrict__ gamma,
           const float* __restrict__ beta, float* __restrict__ out) {
    int n = blockIdx.x;
    int col = threadIdx.x * 8;
    float mx[8];
    {
        uint4 p = *(const uint4*)(out_pre + (size_t)n * DOUT + col);
        mx[0] = bflo(p.x); mx[1] = bfhi(p.x); mx[2] = bflo(p.y); mx[3] = bfhi(p.y);
        mx[4] = bflo(p.z); mx[5] = bfhi(p.z); mx[6] = bflo(p.w); mx[7] = bfhi(p.w);
    }
    int s = offsets[n], e = offsets[n + 1];
    int i = s;
    for (; i + 1 < e; i += 2) {
        int u0 = eidx[i], u1 = eidx[i + 1];
        uint4 p = *(const uint4*)(out_pre + (size_t)u0 * DOUT + col);
        uint4 qq = *(const uint4*)(out_pre + (size_t)u1 * DOUT + col);
        mx[0] = fmaxf(mx[0], fmaxf(bflo(p.x), bflo(qq.x)));
        mx[1] = fmaxf(mx[1], fmaxf(bfhi(p.x), bfhi(qq.x)));
        mx[2] = fmaxf(mx[2], fmaxf(bflo(p.y), bflo(qq.y)));
        mx[3] = fmaxf(mx[3], fmaxf(bfhi(p.y), bfhi(qq.y)));
        mx[4] = fmaxf(mx[4], fmaxf(bflo(p.z), bflo(qq.z)));
        mx[5] = fmaxf(mx[5], fmaxf(bfhi(p.z), bfhi(qq.z)));
        mx[6] = fmaxf(mx[6], fmaxf(bflo(p.w), bflo(qq.w)));
        mx[7] = fmaxf(mx[7], fmaxf(bfhi(p.w), bfhi(qq.w)));
    }
    if (i < e) {
        int u = eidx[i];
        uint4 p = *(const uint4*)(out_pre + (size_t)u * DOUT + col);
        mx[0] = fmaxf(mx[0], bflo(p.x)); mx[1] = fmaxf(mx[1], bfhi(p.x));
        mx[2] = fmaxf(mx[2], bflo(p.y)); mx[3] = fmaxf(mx[3], bfhi(p.y));
        mx[4] = fmaxf(mx[4], bflo(p.z)); mx[5] = fmaxf(mx[5], bfhi(p.z));
        mx[6] = fmaxf(mx[6], bflo(p.w)); mx[7] = fmaxf(mx[7], bfhi(p.w));
    }
    // BN final for these 8 columns
    const float inv_n = 1.0f / (float)N_NODES;
    f32x4 r0, r1;
#pragma unroll
    for (int jj = 0; jj < 8; ++jj) {
        int c = col + jj;
        float mean = bn_sum[c] * inv_n;
        float var = bn_sumsq[c] * inv_n - mean * mean;
        float sc = gamma[c] * rsqrtf(var + BN_EPS);
        float sh = beta[c] - mean * sc;
        float v = mx[jj] * sc + sh;
        if (jj < 4) r0[jj] = v; else r1[jj - 4] = v;
    }
    *(f32x4*)(out + (size_t)n * DOUT + col) = r0;
    *(f32x4*)(out + (size_t)n * DOUT + col + 4) = r1;
}

extern "C" void kernel_launch(void* const* d_in, const int* in_sizes, int n_in,
                              void* d_out, int out_size, void* d_ws, size_t ws_size,
                              hipStream_t stream) {
    const float* feats = (const float*)d_in[0];
    const int*   src   = (const int*)d_in[1];
    const int*   dst   = (const int*)d_in[2];
    const float* Wl    = (const float*)d_in[3];
    const float* Wr    = (const float*)d_in[4];
    const float* bl    = (const float*)d_in[5];
    const float* gamma = (const float*)d_in[6];
    const float* beta  = (const float*)d_in[7];
    float* out = (float*)d_out;

    char* ws = (char*)d_ws;
    size_t off = 0;
    auto alloc = [&](size_t bytes) -> void* {
        off = (off + 255) & ~(size_t)255;
        void* p = ws + off;
        off += bytes;
        return p;
    };

    // zero-initialized region (contiguous & first)
    int*   deg        = (int*)alloc(N_NODES * 4);
    int*   cursor     = (int*)alloc(N_NODES * 4);
    int*   bucket_cnt = (int*)alloc(16 * 4);
    float* bn_sum     = (float*)alloc(DOUT * 4);
    float* bn_sumsq   = (float*)alloc(DOUT * 4);
    size_t zbytes = off;

    int* offsets      = (int*)alloc((N_NODES + 1) * 4);
    int* bucket_nodes = (int*)alloc((size_t)NBUCKET * N_NODES * 4);
    int* eidx         = (int*)alloc(N_EDGES * 4);
    int2* tiles       = (int2*)alloc(MAXTILES * 8);
    int* tile_cnt     = (int*)alloc(4);
    unsigned short* X  = (unsigned short*)alloc((size_t)N_NODES * KDIM * 2);
    unsigned short* Wt = (unsigned short*)alloc((size_t)NBUCKET * DOUT * KDIM * 2);
    unsigned short* out_pre = (unsigned short*)alloc((size_t)N_NODES * DOUT * 2);

    hipMemsetAsync(d_ws, 0, zbytes, stream);

    k_deg<<<(N_EDGES + 255) / 256, 256, 0, stream>>>(dst, deg);
    k_scan<<<1, 1024, 0, stream>>>(deg, offsets);
    k_bucket<<<(N_NODES + 255) / 256, 256, 0, stream>>>(deg, bucket_cnt, bucket_nodes);
    k_tiles<<<1, 64, 0, stream>>>(bucket_cnt, tiles, tile_cnt);
    k_scatter<<<(N_EDGES + 255) / 256, 256, 0, stream>>>(src, dst, offsets, cursor, eidx);
    k_prep<<<CAST_BLOCKS + WT_BLOCKS, 256, 0, stream>>>(feats, Wl, Wr, X, Wt);
    k_build_x<<<N_NODES, 64, 0, stream>>>(eidx, offsets, X);
    k_gemm<<<dim3(MAXTILES, 4), 256, 0, stream>>>(
        X, Wt, tiles, tile_cnt, bucket_nodes, bucket_cnt, bl, out_pre, bn_sum, bn_sumsq);
    k_max<<<N_NODES, 64, 0, stream>>>(out_pre, eidx, offsets, bn_sum, bn_sumsq, gamma, beta, out);
}